// Round 11
// baseline (344.043 us; speedup 1.0000x reference)
//
#include <hip/hip_runtime.h>
#include <hip/hip_bf16.h>

#define B_ 2
#define L_ 2048
#define E_ 2048
#define H_ 16
#define D_ 128
#define M_ (B_*L_)
#define NT_ (E_/64)
#define LOGIT_SCALE_MAX_ 4.6051701859880914f
#define LOG2E_ 1.44269504088896f

typedef __bf16 bf16_t;
typedef __bf16 bf16x2 __attribute__((ext_vector_type(2)));
typedef __bf16 bf16x4 __attribute__((ext_vector_type(4)));
typedef __bf16 bf16x8 __attribute__((ext_vector_type(8)));
typedef float f32x4 __attribute__((ext_vector_type(4)));
typedef float f32x16 __attribute__((ext_vector_type(16)));

// attn LDS: double-buffered K (64x128 @256B rows) + V^T (128x64 @128B rows), 32KB per buffer
#define KSB(p, r, cb) ((p) * 32768 + (r) * 256 + ((cb) ^ (((r) & 7) << 4)))
#define VSB(p, r, cb) ((p) * 32768 + 16384 + (r) * 128 + ((cb) ^ (((r) & 7) << 4)))

// GEMM LDS tile: 128 rows x 64 bf16; chunk-XOR swizzled content (conflict-free, PMC=0)
#define GEMM_FRAG_IDX(r, kk, fq) ((r) * 64 + ((((kk) * 4 + (fq)) ^ ((r) & 7)) * 8))

// ---------------- fused fp32 -> bf16 convert of all 7 inputs ----------------
#define NW_ 4194304L   // E*E
#define NX_ 8388608L   // M*E
__global__ void cvt_all_k(const float* __restrict__ xq, const float* __restrict__ xkv,
                          const float* __restrict__ bias,
                          const float* __restrict__ wq, const float* __restrict__ wk,
                          const float* __restrict__ wv, const float* __restrict__ wo,
                          bf16_t* __restrict__ ws) {
    const long NW4 = NW_ / 4, NX4 = NX_ / 4;
    long i4 = (long)blockIdx.x * 256 + threadIdx.x;
    const float* src; long off; float scale = 1.0f;
    if (i4 < 4 * NW4) {
        long r = i4 / NW4;
        src = (r == 0) ? wq : (r == 1) ? wk : (r == 2) ? wv : wo;
        off = i4 - r * NW4;
    } else if (i4 < 5 * NW4) {
        src = bias; off = i4 - 4 * NW4; scale = LOG2E_;
    } else if (i4 < 5 * NW4 + NX4) {
        src = xq; off = i4 - 5 * NW4;
    } else {
        src = xkv; off = i4 - 5 * NW4 - NX4;
    }
    float4 v = ((const float4*)src)[off];
    bf16x4 o = { (bf16_t)(v.x * scale), (bf16_t)(v.y * scale),
                 (bf16_t)(v.z * scale), (bf16_t)(v.w * scale) };
    ((bf16x4*)ws)[i4] = o;
}

// ---------------- pipelined NT GEMM, optionally with fused postproc epilogue ----------------
// FUSE=true (GROUPS=3, QKV): g=0/1 -> RMS+RoPE+L2 -> Qn/Kn [b,h,l,d]; g=2 -> transpose -> Vt [b,h,d,l].
// FUSE=false: plain C store (O projection).
template<typename OutT, int GROUPS, bool FUSE>
__global__ __launch_bounds__(256, 4) void gemm_pipe(
    const bf16_t* __restrict__ A0, const bf16_t* __restrict__ A1,
    const bf16_t* __restrict__ W0, OutT* __restrict__ C0,
    const float* __restrict__ sq, const float* __restrict__ sk,
    const float* __restrict__ nq, const float* __restrict__ nk,
    bf16_t* __restrict__ Qn, bf16_t* __restrict__ Kn, bf16_t* __restrict__ Vt) {
    __shared__ bf16_t As[2][128 * 64];
    __shared__ bf16_t Bs[2][128 * 64];
    const int tid = threadIdx.x;
    const int wid = tid >> 6, lane = tid & 63;
    int bid = blockIdx.x;
    {
        int cpx = (int)gridDim.x >> 3;
        bid = (bid & 7) * cpx + (bid >> 3);
    }
    const int g = bid >> 9;
    const int wg = bid & 511;
    const int bm = wg >> 4, bn = wg & 15;
    const long arow0 = (long)bm * 128;
    const long brow0 = (long)bn * 128;
    const int fr = lane & 15, fq = lane >> 4;
    const int srow = lane >> 3;
    const int scol = ((lane & 7) ^ srow) * 8;   // pre-swizzled source col
    const int wm = wid >> 1, wn = wid & 1;
    const bf16_t* Ab = ((GROUPS > 1 && g > 0) ? A1 : A0) + arow0 * E_;
    const bf16_t* Wb = W0 + (long)g * E_ * E_ + brow0 * E_;

    f32x4 acc[4][4] = {};

    auto STAGE = [&](int kt, int p) {
        #pragma unroll
        for (int q = 0; q < 4; ++q) {
            int row = wid * 32 + q * 8 + srow;
            __builtin_amdgcn_global_load_lds(
                (const __attribute__((address_space(1))) void*)(Ab + (long)row * E_ + kt + scol),
                (__attribute__((address_space(3))) void*)(&As[p][(wid * 32 + q * 8) * 64]), 16, 0, 0);
            __builtin_amdgcn_global_load_lds(
                (const __attribute__((address_space(1))) void*)(Wb + (long)row * E_ + kt + scol),
                (__attribute__((address_space(3))) void*)(&Bs[p][(wid * 32 + q * 8) * 64]), 16, 0, 0);
        }
    };

    STAGE(0, 0);
    int p = 0;
    bf16x8 a[2][4], b[2][4];
    for (int t = 0; t < NT_ - 1; ++t) {
        STAGE((t + 1) * 64, p ^ 1);
        asm volatile("s_waitcnt vmcnt(8)" ::: "memory");
        __builtin_amdgcn_s_barrier();
        __builtin_amdgcn_sched_barrier(0);
        #pragma unroll
        for (int kk = 0; kk < 2; ++kk) {
            #pragma unroll
            for (int mi = 0; mi < 4; ++mi)
                a[kk][mi] = *(const bf16x8*)&As[p][GEMM_FRAG_IDX(wm * 64 + mi * 16 + fr, kk, fq)];
            #pragma unroll
            for (int ni = 0; ni < 4; ++ni)
                b[kk][ni] = *(const bf16x8*)&Bs[p][GEMM_FRAG_IDX(wn * 64 + ni * 16 + fr, kk, fq)];
        }
        asm volatile("s_waitcnt lgkmcnt(0)" ::: "memory");
        __builtin_amdgcn_sched_barrier(0);
        __builtin_amdgcn_s_barrier();
        __builtin_amdgcn_s_setprio(1);
        #pragma unroll
        for (int kk = 0; kk < 2; ++kk)
            #pragma unroll
            for (int mi = 0; mi < 4; ++mi)
                #pragma unroll
                for (int ni = 0; ni < 4; ++ni)
                    acc[mi][ni] = __builtin_amdgcn_mfma_f32_16x16x32_bf16(a[kk][mi], b[kk][ni], acc[mi][ni], 0, 0, 0);
        __builtin_amdgcn_s_setprio(0);
        p ^= 1;
    }
    asm volatile("s_waitcnt vmcnt(0)" ::: "memory");
    __builtin_amdgcn_s_barrier();
    __builtin_amdgcn_sched_barrier(0);
    #pragma unroll
    for (int kk = 0; kk < 2; ++kk) {
        #pragma unroll
        for (int mi = 0; mi < 4; ++mi)
            a[kk][mi] = *(const bf16x8*)&As[p][GEMM_FRAG_IDX(wm * 64 + mi * 16 + fr, kk, fq)];
        #pragma unroll
        for (int ni = 0; ni < 4; ++ni)
            b[kk][ni] = *(const bf16x8*)&Bs[p][GEMM_FRAG_IDX(wn * 64 + ni * 16 + fr, kk, fq)];
        #pragma unroll
        for (int mi = 0; mi < 4; ++mi)
            #pragma unroll
            for (int ni = 0; ni < 4; ++ni)
                acc[mi][ni] = __builtin_amdgcn_mfma_f32_16x16x32_bf16(a[kk][mi], b[kk][ni], acc[mi][ni], 0, 0, 0);
    }

    if constexpr (FUSE) {
        // ---- fused epilogue: acc -> LDS f32 tile (chunk-XOR swizzled) -> postproc/transpose ----
        __syncthreads();                 // all waves done with As/Bs reads
        float* eps = (float*)&As[0][0];  // 64 KB = 128x128 f32
        #pragma unroll
        for (int mi = 0; mi < 4; ++mi)
            #pragma unroll
            for (int i = 0; i < 4; ++i) {
                int rl = wm * 64 + mi * 16 + fq * 4 + i;
                #pragma unroll
                for (int ni = 0; ni < 4; ++ni) {
                    int c = wn * 64 + ni * 16 + fr;
                    eps[rl * 128 + ((((c >> 2) ^ (rl & 7)) << 2) | (c & 3))] = acc[mi][ni][i];
                }
            }
        __syncthreads();
        const int r = tid >> 1, hf = tid & 1;
        if (g < 2) {
            const float* sins = (g == 0) ? sq : sk;
            const float* nsc  = (g == 0) ? nq : nk;
            bf16_t* outb      = (g == 0) ? Qn : Kn;
            const int rowg = (int)arow0 + r;
            const int bb2 = rowg >> 11, ll = rowg & 2047;
            const float* sinrow = sins + (long)rowg * 128 + hf * 64;
            float ss = 0.f;
            #pragma unroll
            for (int c = 0; c < 16; ++c) {
                float4 v = *(float4*)&eps[r * 128 + (((hf * 16 + c) ^ (r & 7)) << 2)];
                ss += v.x * v.x + v.y * v.y + v.z * v.z + v.w * v.w;
            }
            ss += __shfl_xor(ss, 1);
            float rms = rsqrtf(ss * (1.f / 128.f) + 1e-6f);
            float n2 = 0.f;
            #pragma unroll
            for (int c = 0; c < 16; ++c) {
                int ix = r * 128 + (((hf * 16 + c) ^ (r & 7)) << 2);
                float4 v = *(float4*)&eps[ix];
                float4 s4 = *(const float4*)&sinrow[c * 4];
                float4 n4 = *(const float4*)&nsc[hf * 64 + c * 4];
                float y0 = v.x * rms * n4.x, y1 = v.y * rms * n4.y;
                float y2 = v.z * rms * n4.z, y3 = v.w * rms * n4.w;
                float4 z;
                z.x = y0 * s4.x - y1 * s4.y;  z.y = y1 * s4.x + y0 * s4.y;
                z.z = y2 * s4.z - y3 * s4.w;  z.w = y3 * s4.z + y2 * s4.w;
                n2 += z.x * z.x + z.y * z.y + z.z * z.z + z.w * z.w;
                *(float4*)&eps[ix] = z;
            }
            n2 += __shfl_xor(n2, 1);
            float inv = 1.f / fmaxf(sqrtf(n2), 1e-12f);
            bf16_t* outp = outb + (((long)bb2 * H_ + bn) * L_ + ll) * D_ + hf * 64;
            #pragma unroll
            for (int c2 = 0; c2 < 8; ++c2) {
                float4 v0 = *(float4*)&eps[r * 128 + (((hf * 16 + c2 * 2)     ^ (r & 7)) << 2)];
                float4 v1 = *(float4*)&eps[r * 128 + (((hf * 16 + c2 * 2 + 1) ^ (r & 7)) << 2)];
                bf16x8 o = { (bf16_t)(v0.x * inv), (bf16_t)(v0.y * inv), (bf16_t)(v0.z * inv), (bf16_t)(v0.w * inv),
                             (bf16_t)(v1.x * inv), (bf16_t)(v1.y * inv), (bf16_t)(v1.z * inv), (bf16_t)(v1.w * inv) };
                *(bf16x8*)(outp + c2 * 8) = o;
            }
        } else {
            // V: transpose to Vt[b,h,d,l]; r = d, hf picks l-half
            bf16_t* vout = Vt + (((long)(bm >> 4) * H_ + bn) * D_ + r) * L_ + (bm & 15) * 128 + hf * 64;
            #pragma unroll
            for (int c8 = 0; c8 < 8; ++c8) {
                bf16x8 o;
                #pragma unroll
                for (int j = 0; j < 8; ++j) {
                    int l = hf * 64 + c8 * 8 + j;
                    o[j] = (bf16_t)eps[l * 128 + ((((r >> 2) ^ (l & 7)) << 2) | (r & 3))];
                }
                *(bf16x8*)(vout + c8 * 8) = o;
            }
        }
    } else {
        OutT* Cg = C0 + (long)g * M_ * E_;
        #pragma unroll
        for (int mi = 0; mi < 4; ++mi) {
            #pragma unroll
            for (int i = 0; i < 4; ++i) {
                long row = arow0 + wm * 64 + mi * 16 + fq * 4 + i;
                OutT* crow = Cg + row * E_ + brow0 + wn * 64 + fr;
                #pragma unroll
                for (int ni = 0; ni < 4; ++ni)
                    crow[ni * 16] = (OutT)acc[mi][ni][i];
            }
        }
    }
}

// ---------------- flash attention (32x32 MFMA, swapped operands, no-max softmax,
//                   double-buffered LDS -> single barrier per KV tile) ----------------
__global__ __launch_bounds__(256, 2) void attn_k(
    const bf16_t* __restrict__ Qn, const bf16_t* __restrict__ Kn,
    const bf16_t* __restrict__ Vt, const bf16_t* __restrict__ biasb,
    const float* __restrict__ lsg, bf16_t* __restrict__ AO) {
    __shared__ __align__(16) unsigned char smem[65536];
    const int tid = threadIdx.x;
    const int w = tid >> 6, lane = tid & 63;
    const int lane31 = lane & 31, hi = lane >> 5;
    const int qb = blockIdx.x, bh = blockIdx.y;
    const int b = bh >> 4, h = bh & 15;
    const float lsc2 = __expf(fminf(lsg[h], LOGIT_SCALE_MAX_)) * LOG2E_;
    const int qr0 = qb * 128;
    const int qloc = w * 32 + lane31;
    const bf16_t* qrow  = Qn + (((long)b * H_ + h) * L_ + qr0 + qloc) * D_;
    const bf16_t* kbase = Kn + (((long)b * H_ + h) * L_) * D_;
    const bf16_t* vtbase = Vt + ((long)(b * H_ + h) * D_) * L_;
    const bf16_t* brow  = biasb + (long)(qr0 + qloc) * L_;

    const int ksr = tid >> 4, ksc = (tid & 15) * 8;
    const int vsr = tid >> 3, vsc = (tid & 7) * 8;

    bf16x8 qreg[8];
    #pragma unroll
    for (int kk = 0; kk < 8; ++kk)
        qreg[kk] = *(const bf16x8*)(qrow + kk * 16 + 8 * hi);

    f32x16 oacc[4] = {};
    float l_ = 0.f;

    bf16x8 kreg[4], vreg[4];
    #pragma unroll
    for (int it = 0; it < 4; ++it) {
        kreg[it] = *(const bf16x8*)(kbase + (long)(it * 16 + ksr) * D_ + ksc);
        vreg[it] = *(const bf16x8*)(vtbase + (long)(it * 32 + vsr) * L_ + vsc);
    }
    #pragma unroll
    for (int it = 0; it < 4; ++it) {
        *(bf16x8*)(smem + KSB(0, it * 16 + ksr, ksc * 2)) = kreg[it];
        *(bf16x8*)(smem + VSB(0, it * 32 + vsr, vsc * 2)) = vreg[it];
    }
    int p = 0;

    for (int kt = 0; kt < L_; kt += 64) {
        __syncthreads();   // buf[p] visible; buf[p^1] free
        const int ktn = (kt + 64 < L_) ? kt + 64 : 0;
        #pragma unroll
        for (int it = 0; it < 4; ++it) {
            kreg[it] = *(const bf16x8*)(kbase + (long)(ktn + it * 16 + ksr) * D_ + ksc);
            vreg[it] = *(const bf16x8*)(vtbase + (long)(it * 32 + vsr) * L_ + ktn + vsc);
        }
        bf16x4 bb[2][4];
        #pragma unroll
        for (int f = 0; f < 2; ++f)
            #pragma unroll
            for (int rr = 0; rr < 4; ++rr)
                bb[f][rr] = *(const bf16x4*)(brow + kt + f * 32 + rr * 8 + 4 * hi);
        f32x16 sacc[2] = {};
        __builtin_amdgcn_s_setprio(1);
        #pragma unroll
        for (int kk = 0; kk < 8; ++kk) {
            bf16x8 ak0 = *(const bf16x8*)(smem + KSB(p, lane31,      kk * 32 + 16 * hi));
            bf16x8 ak1 = *(const bf16x8*)(smem + KSB(p, 32 + lane31, kk * 32 + 16 * hi));
            sacc[0] = __builtin_amdgcn_mfma_f32_32x32x16_bf16(ak0, qreg[kk], sacc[0], 0, 0, 0);
            sacc[1] = __builtin_amdgcn_mfma_f32_32x32x16_bf16(ak1, qreg[kk], sacc[1], 0, 0, 0);
        }
        __builtin_amdgcn_s_setprio(0);
        float ps = 0.f;
        unsigned int wv[2][4][2];
        #pragma unroll
        for (int f = 0; f < 2; ++f)
            #pragma unroll
            for (int rr = 0; rr < 4; ++rr)
                #pragma unroll
                for (int wi = 0; wi < 2; ++wi) {
                    float pa = __builtin_amdgcn_exp2f(sacc[f][rr * 4 + wi * 2]     * lsc2 + (float)bb[f][rr][wi * 2]);
                    float pc = __builtin_amdgcn_exp2f(sacc[f][rr * 4 + wi * 2 + 1] * lsc2 + (float)bb[f][rr][wi * 2 + 1]);
                    ps += pa + pc;
                    bf16x2 t = { (bf16_t)pa, (bf16_t)pc };
                    wv[f][rr][wi] = __builtin_bit_cast(unsigned int, t);
                }
        ps += __shfl_xor(ps, 32);
        l_ += ps;
        bf16x8 pb_[4];
        #pragma unroll
        for (int kk = 0; kk < 4; ++kk) {
            const int f = kk >> 1;
            const int a2 = (kk & 1) * 2;
            unsigned int A0 = wv[f][a2][0],     A1 = wv[f][a2][1];
            unsigned int B0 = wv[f][a2 + 1][0], B1 = wv[f][a2 + 1][1];
            unsigned int own0  = hi ? B0 : A0;
            unsigned int own1  = hi ? B1 : A1;
            unsigned int send0 = hi ? A0 : B0;
            unsigned int send1 = hi ? A1 : B1;
            unsigned int recv0 = __shfl_xor(send0, 32);
            unsigned int recv1 = __shfl_xor(send1, 32);
            uint4 uu;
            uu.x = hi ? recv0 : own0;
            uu.y = hi ? recv1 : own1;
            uu.z = hi ? own0  : recv0;
            uu.w = hi ? own1  : recv1;
            pb_[kk] = __builtin_bit_cast(bf16x8, uu);
        }
        __builtin_amdgcn_s_setprio(1);
        #pragma unroll
        for (int df = 0; df < 4; ++df)
            #pragma unroll
            for (int kk = 0; kk < 4; ++kk) {
                bf16x8 av = *(const bf16x8*)(smem + VSB(p, df * 32 + lane31, kk * 32 + 16 * hi));
                oacc[df] = __builtin_amdgcn_mfma_f32_32x32x16_bf16(av, pb_[kk], oacc[df], 0, 0, 0);
            }
        __builtin_amdgcn_s_setprio(0);
        if (kt + 64 < L_) {
            #pragma unroll
            for (int it = 0; it < 4; ++it) {
                *(bf16x8*)(smem + KSB(p ^ 1, it * 16 + ksr, ksc * 2)) = kreg[it];
                *(bf16x8*)(smem + VSB(p ^ 1, it * 32 + vsr, vsc * 2)) = vreg[it];
            }
        }
        p ^= 1;
    }
    __syncthreads();
    float inv = 1.0f / l_;
    #pragma unroll
    for (int df = 0; df < 4; ++df)
        #pragma unroll
        for (int rg = 0; rg < 16; ++rg) {
            int d = df * 32 + (rg & 3) + 8 * (rg >> 2) + 4 * hi;
            *(bf16_t*)(smem + qloc * 264 + d * 2) = (bf16_t)(oacc[df][rg] * inv);
        }
    __syncthreads();
    #pragma unroll
    for (int it = 0; it < 8; ++it) {
        int idx = it * 256 + tid;
        int row = idx >> 4, c = idx & 15;
        bf16x8 v = *(const bf16x8*)(smem + row * 264 + c * 16);
        *(bf16x8*)(AO + ((long)b * L_ + qr0 + row) * E_ + h * D_ + c * 8) = v;
    }
}

extern "C" void kernel_launch(void* const* d_in, const int* in_sizes, int n_in,
                              void* d_out, int out_size, void* d_ws, size_t ws_size,
                              hipStream_t stream) {
    const float* inputs_q  = (const float*)d_in[0];
    const float* inputs_kv = (const float*)d_in[1];
    const float* bias      = (const float*)d_in[2];
    const float* q_sin     = (const float*)d_in[3];
    const float* k_sin     = (const float*)d_in[4];
    const float* Wq        = (const float*)d_in[5];
    const float* Wk        = (const float*)d_in[6];
    const float* Wv        = (const float*)d_in[7];
    const float* Wo        = (const float*)d_in[8];
    const float* qns       = (const float*)d_in[9];
    const float* kns       = (const float*)d_in[10];
    const float* lsg       = (const float*)d_in[11];

    bf16_t* ws = (bf16_t*)d_ws;
    const long NW = NW_;
    const long NX = NX_;
    bf16_t* Wq_b   = ws;                    // Wq,Wk,Wv contiguous
    bf16_t* Wo_b   = ws + 3 * NW;
    bf16_t* bias_b = ws + 4 * NW;
    bf16_t* Xq     = bias_b + NW;
    bf16_t* Xkv    = Xq + NX;
    bf16_t* Qn     = Xkv + NX;
    bf16_t* Kn     = Qn + NX;
    bf16_t* Vtr    = Kn + NX;
    bf16_t* AO     = Xq;   // alias (Xq dead after QKV GEMM)
    if (ws_size < (size_t)(5 * NW + 5 * NX) * 2) return;

    {
        long n4 = (5 * NW + 2 * NX) / 4;
        cvt_all_k<<<dim3((unsigned)(n4 / 256)), dim3(256), 0, stream>>>(
            inputs_q, inputs_kv, bias, Wq, Wk, Wv, Wo, ws);
    }

    // QKV projection with fused RMS/RoPE/L2 (Q,K) and transpose (V)
    gemm_pipe<bf16_t, 3, true><<<dim3(1536), dim3(256), 0, stream>>>(
        Xq, Xkv, Wq_b, (bf16_t*)nullptr, q_sin, k_sin, qns, kns, Qn, Kn, Vtr);

    attn_k<<<dim3(L_ / 128, B_ * H_), dim3(256), 0, stream>>>(Qn, Kn, Vtr, bias_b, lsg, AO);

    gemm_pipe<float, 1, false><<<dim3(512), dim3(256), 0, stream>>>(
        AO, AO, Wo_b, (float*)d_out, nullptr, nullptr, nullptr, nullptr, nullptr, nullptr, nullptr);
}

// Round 12
// 319.967 us; speedup vs baseline: 1.0752x; 1.0752x over previous
//
#include <hip/hip_runtime.h>
#include <hip/hip_bf16.h>

#define B_ 2
#define L_ 2048
#define E_ 2048
#define H_ 16
#define D_ 128
#define M_ (B_*L_)
#define LOGIT_SCALE_MAX_ 4.6051701859880914f
#define LOG2E_ 1.44269504088896f

typedef __bf16 bf16_t;
typedef __bf16 bf16x2 __attribute__((ext_vector_type(2)));
typedef __bf16 bf16x4 __attribute__((ext_vector_type(4)));
typedef __bf16 bf16x8 __attribute__((ext_vector_type(8)));
typedef float f32x4 __attribute__((ext_vector_type(4)));
typedef float f32x16 __attribute__((ext_vector_type(16)));

// attn LDS: double-buffered K (64x128 @256B rows) + V^T (128x64 @128B rows), 32KB per buffer
#define KSB(p, r, cb) ((p) * 32768 + (r) * 256 + ((cb) ^ (((r) & 7) << 4)))
#define VSB(p, r, cb) ((p) * 32768 + 16384 + (r) * 128 + ((cb) ^ (((r) & 7) << 4)))

#define NW_ 4194304L   // E*E
#define NX_ 8388608L   // M*E

// ---------------- fused fp32 -> bf16 convert of all 7 inputs ----------------
__global__ void cvt_all_k(const float* __restrict__ xq, const float* __restrict__ xkv,
                          const float* __restrict__ bias,
                          const float* __restrict__ wq, const float* __restrict__ wk,
                          const float* __restrict__ wv, const float* __restrict__ wo,
                          bf16_t* __restrict__ ws) {
    const long NW4 = NW_ / 4, NX4 = NX_ / 4;
    long i4 = (long)blockIdx.x * 256 + threadIdx.x;
    const float* src; long off; float scale = 1.0f;
    if (i4 < 4 * NW4) {
        long r = i4 / NW4;
        src = (r == 0) ? wq : (r == 1) ? wk : (r == 2) ? wv : wo;
        off = i4 - r * NW4;
    } else if (i4 < 5 * NW4) {
        src = bias; off = i4 - 4 * NW4; scale = LOG2E_;
    } else if (i4 < 5 * NW4 + NX4) {
        src = xq; off = i4 - 5 * NW4;
    } else {
        src = xkv; off = i4 - 5 * NW4 - NX4;
    }
    float4 v = ((const float4*)src)[off];
    bf16x4 o = { (bf16_t)(v.x * scale), (bf16_t)(v.y * scale),
                 (bf16_t)(v.z * scale), (bf16_t)(v.w * scale) };
    ((bf16x4*)ws)[i4] = o;
}

// ---------------- 8-phase 256x128 NT GEMM: C[M,2048] = A * W[2048,2048]^T ----------------
// 8 waves (4M x 2N), BK=64 split into two kk sub-tiles [rows][32] (64B rows, XOR swizzle).
// Staging of tile t+1 spread across phases; counted vmcnt(3) at phases 1 and 3 only.
// LDS per buffer 48KB: A_kk0 | A_kk1 | B_kk0 | B_kk1 ; double-buffered -> 96KB.
template<typename OutT, int GROUPS>
__global__ __launch_bounds__(512, 2) void gemm8(
    const bf16_t* __restrict__ A0g, const bf16_t* __restrict__ A1g,
    const bf16_t* __restrict__ W0, OutT* __restrict__ C0) {
    __shared__ __align__(16) unsigned char smem[98304];
    const int tid = threadIdx.x;
    const int wid = tid >> 6, lane = tid & 63;
    const int fr = lane & 15, fq = lane >> 4;
    const int wm = wid & 3, wn = wid >> 2;
    int bid = blockIdx.x;
    { int cpx = (int)gridDim.x >> 3; bid = (bid & 7) * cpx + (bid >> 3); }
    const int g = (GROUPS > 1) ? (bid >> 8) : 0;
    const int wg = bid & 255;
    const int bm = wg >> 4, bn = wg & 15;
    const long arow0 = (long)bm * 256;
    const long brow0 = (long)bn * 128;
    const bf16_t* Ab = ((GROUPS > 1 && g > 0) ? A1g : A0g) + arow0 * E_;
    const bf16_t* Wb = W0 + (long)g * (long)E_ * E_ + brow0 * E_;

    f32x4 acc[4][4] = {};

    // staging: per-thread one 16B gload_lds per "issue"; A kk-subtile = 2 issues, B = 1
    auto STAGE_A = [&](unsigned sbase, int kk, int j, int ktn_) {
        int row = j * 128 + (tid >> 2);
        int c16 = tid & 3;
        int col = kk * 32 + ((c16 ^ ((row >> 1) & 3)) * 8);
        __builtin_amdgcn_global_load_lds(
            (const __attribute__((address_space(1))) void*)(Ab + (long)row * E_ + ktn_ + col),
            (__attribute__((address_space(3))) void*)(smem + sbase + kk * 16384 + j * 8192 + tid * 16), 16, 0, 0);
    };
    auto STAGE_B = [&](unsigned sbase, int kk, int ktn_) {
        int row = tid >> 2;
        int c16 = tid & 3;
        int col = kk * 32 + ((c16 ^ ((row >> 1) & 3)) * 8);
        __builtin_amdgcn_global_load_lds(
            (const __attribute__((address_space(1))) void*)(Wb + (long)row * E_ + ktn_ + col),
            (__attribute__((address_space(3))) void*)(smem + sbase + 32768 + kk * 8192 + tid * 16), 16, 0, 0);
    };
    auto LDA = [&](unsigned pbase, int kk, int mi) -> bf16x8 {
        int row = wm * 64 + mi * 16 + fr;
        return *(const bf16x8*)(smem + pbase + kk * 16384 + row * 64 + ((fq ^ ((row >> 1) & 3)) << 4));
    };
    auto LDB = [&](unsigned pbase, int kk, int ni) -> bf16x8 {
        int row = wn * 64 + ni * 16 + fr;
        return *(const bf16x8*)(smem + pbase + 32768 + kk * 8192 + row * 64 + ((fq ^ ((row >> 1) & 3)) << 4));
    };

    // prologue: tile 0 fully staged, drained once
    STAGE_A(0, 0, 0, 0); STAGE_A(0, 0, 1, 0); STAGE_B(0, 0, 0);
    STAGE_A(0, 1, 0, 0); STAGE_A(0, 1, 1, 0); STAGE_B(0, 1, 0);
    asm volatile("s_waitcnt vmcnt(0)" ::: "memory");
    __builtin_amdgcn_s_barrier();

    #pragma unroll 2
    for (int t = 0; t < 32; ++t) {
        const unsigned pb = (unsigned)(t & 1) * 49152u;   // read buffer
        const unsigned sb = 49152u - pb;                  // stage buffer
        const int ktn = (t < 31) ? (t + 1) * 64 : 0;
        bf16x8 bq[4], a0, a1;
        // ---- phase 0: kk0, m-frags 0/1 ; stage A_kk0(t+1)
        a0 = LDA(pb, 0, 0); a1 = LDA(pb, 0, 1);
        bq[0] = LDB(pb, 0, 0); bq[1] = LDB(pb, 0, 1); bq[2] = LDB(pb, 0, 2); bq[3] = LDB(pb, 0, 3);
        STAGE_A(sb, 0, 0, ktn); STAGE_A(sb, 0, 1, ktn);
        __builtin_amdgcn_s_barrier();
        asm volatile("s_waitcnt lgkmcnt(0)" ::: "memory");
        __builtin_amdgcn_sched_barrier(0);
        __builtin_amdgcn_s_setprio(1);
        #pragma unroll
        for (int ni = 0; ni < 4; ++ni) {
            acc[0][ni] = __builtin_amdgcn_mfma_f32_16x16x32_bf16(a0, bq[ni], acc[0][ni], 0, 0, 0);
            acc[1][ni] = __builtin_amdgcn_mfma_f32_16x16x32_bf16(a1, bq[ni], acc[1][ni], 0, 0, 0);
        }
        __builtin_amdgcn_s_setprio(0);
        __builtin_amdgcn_s_barrier();
        // ---- phase 1: kk0, m-frags 2/3 ; stage B_kk0(t+1) ; vmcnt(3)
        a0 = LDA(pb, 0, 2); a1 = LDA(pb, 0, 3);
        STAGE_B(sb, 0, ktn);
        asm volatile("s_waitcnt vmcnt(3)" ::: "memory");
        __builtin_amdgcn_s_barrier();
        asm volatile("s_waitcnt lgkmcnt(0)" ::: "memory");
        __builtin_amdgcn_sched_barrier(0);
        __builtin_amdgcn_s_setprio(1);
        #pragma unroll
        for (int ni = 0; ni < 4; ++ni) {
            acc[2][ni] = __builtin_amdgcn_mfma_f32_16x16x32_bf16(a0, bq[ni], acc[2][ni], 0, 0, 0);
            acc[3][ni] = __builtin_amdgcn_mfma_f32_16x16x32_bf16(a1, bq[ni], acc[3][ni], 0, 0, 0);
        }
        __builtin_amdgcn_s_setprio(0);
        __builtin_amdgcn_s_barrier();
        // ---- phase 2: kk1, m-frags 0/1 ; stage A_kk1(t+1)
        a0 = LDA(pb, 1, 0); a1 = LDA(pb, 1, 1);
        bq[0] = LDB(pb, 1, 0); bq[1] = LDB(pb, 1, 1); bq[2] = LDB(pb, 1, 2); bq[3] = LDB(pb, 1, 3);
        STAGE_A(sb, 1, 0, ktn); STAGE_A(sb, 1, 1, ktn);
        __builtin_amdgcn_s_barrier();
        asm volatile("s_waitcnt lgkmcnt(0)" ::: "memory");
        __builtin_amdgcn_sched_barrier(0);
        __builtin_amdgcn_s_setprio(1);
        #pragma unroll
        for (int ni = 0; ni < 4; ++ni) {
            acc[0][ni] = __builtin_amdgcn_mfma_f32_16x16x32_bf16(a0, bq[ni], acc[0][ni], 0, 0, 0);
            acc[1][ni] = __builtin_amdgcn_mfma_f32_16x16x32_bf16(a1, bq[ni], acc[1][ni], 0, 0, 0);
        }
        __builtin_amdgcn_s_setprio(0);
        __builtin_amdgcn_s_barrier();
        // ---- phase 3: kk1, m-frags 2/3 ; stage B_kk1(t+1) ; vmcnt(3)
        a0 = LDA(pb, 1, 2); a1 = LDA(pb, 1, 3);
        STAGE_B(sb, 1, ktn);
        asm volatile("s_waitcnt vmcnt(3)" ::: "memory");
        __builtin_amdgcn_s_barrier();
        asm volatile("s_waitcnt lgkmcnt(0)" ::: "memory");
        __builtin_amdgcn_sched_barrier(0);
        __builtin_amdgcn_s_setprio(1);
        #pragma unroll
        for (int ni = 0; ni < 4; ++ni) {
            acc[2][ni] = __builtin_amdgcn_mfma_f32_16x16x32_bf16(a0, bq[ni], acc[2][ni], 0, 0, 0);
            acc[3][ni] = __builtin_amdgcn_mfma_f32_16x16x32_bf16(a1, bq[ni], acc[3][ni], 0, 0, 0);
        }
        __builtin_amdgcn_s_setprio(0);
        __builtin_amdgcn_s_barrier();
    }
    // C store
    OutT* Cg = C0 + (long)g * M_ * E_;
    #pragma unroll
    for (int mi = 0; mi < 4; ++mi) {
        #pragma unroll
        for (int i = 0; i < 4; ++i) {
            long row = arow0 + wm * 64 + mi * 16 + fq * 4 + i;
            OutT* crow = Cg + row * E_ + brow0 + wn * 64 + fr;
            #pragma unroll
            for (int ni = 0; ni < 4; ++ni)
                crow[ni * 16] = (OutT)acc[mi][ni][i];
        }
    }
}

// ---------------- merged: Q/K postprocess (blocks 0..32767) + V transpose (blocks 32768..34815) ----------------
__global__ __launch_bounds__(256) void post_tv_k(
    const bf16_t* __restrict__ Pq, const bf16_t* __restrict__ Pk,
    const bf16_t* __restrict__ Vp,
    const float* __restrict__ qsins, const float* __restrict__ ksins,
    const float* __restrict__ qnscale, const float* __restrict__ knscale,
    bf16_t* __restrict__ outq, bf16_t* __restrict__ outk, bf16_t* __restrict__ Vt) {
    __shared__ bf16_t t[64 * 64];
    if (blockIdx.x < 32768) {
        const int wid = threadIdx.x >> 6, lane = threadIdx.x & 63;
        const int half = blockIdx.x >> 14;
        const long g = (long)(blockIdx.x & 16383) * 4 + wid;
        const bf16_t* P = half ? Pk : Pq;
        const float* sins = half ? ksins : qsins;
        const float* nscale = half ? knscale : qnscale;
        bf16_t* out = half ? outk : outq;
        const int h = (int)(g % H_);
        const long bl = g / H_;
        const int b = (int)(bl / L_), l = (int)(bl % L_);
        bf16x2 xv = *(const bf16x2*)(P + g * D_ + lane * 2);
        float x0 = (float)xv[0], x1 = (float)xv[1];
        float ss = x0 * x0 + x1 * x1;
        #pragma unroll
        for (int m = 1; m < 64; m <<= 1) ss += __shfl_xor(ss, m);
        float r = rsqrtf(ss * (1.0f / 128.0f) + 1e-6f);
        float y0 = x0 * r * nscale[lane * 2];
        float y1 = x1 * r * nscale[lane * 2 + 1];
        float2 cs = *(const float2*)(sins + bl * D_ + lane * 2);
        float z0 = y0 * cs.x - y1 * cs.y;
        float z1 = y1 * cs.x + y0 * cs.y;
        float n2 = z0 * z0 + z1 * z1;
        #pragma unroll
        for (int m = 1; m < 64; m <<= 1) n2 += __shfl_xor(n2, m);
        float inv = 1.0f / fmaxf(sqrtf(n2), 1e-12f);
        bf16x2 o = { (bf16_t)(z0 * inv), (bf16_t)(z1 * inv) };
        *(bf16x2*)(out + (((long)b * H_ + h) * L_ + l) * D_ + lane * 2) = o;
    } else {
        const int idx = blockIdx.x - 32768;
        const int lb = idx & 31;
        const int db = (idx >> 5) & 1;
        const int bh = idx >> 6;
        const int b = bh >> 4, h = bh & 15;
        const bf16_t* src = Vp + ((long)(b * L_ + lb * 64) * H_ + h) * D_ + db * 64;
        #pragma unroll
        for (int it = 0; it < 2; ++it) {
            int i = it * 256 + threadIdx.x;
            int r = i >> 3, c8 = i & 7;
            bf16x8 v = *(const bf16x8*)(src + (long)r * H_ * D_ + c8 * 8);
            *(bf16x8*)&t[r * 64 + (c8 ^ (r >> 3)) * 8] = v;
        }
        __syncthreads();
        bf16_t* dst = Vt + ((long)(b * H_ + h) * D_ + db * 64) * L_ + lb * 64;
        #pragma unroll
        for (int it = 0; it < 2; ++it) {
            int i = it * 256 + threadIdx.x;
            int d = i >> 3, l8 = i & 7;
            bf16x8 o;
            #pragma unroll
            for (int j = 0; j < 8; ++j) {
                int l = l8 * 8 + j;
                o[j] = t[l * 64 + ((d >> 3) ^ l8) * 8 + (d & 7)];
            }
            *(bf16x8*)(dst + (long)d * L_ + l8 * 8) = o;
        }
    }
}

// ---------------- flash attention (round-9 form: 32x32 swapped, no-max softmax, 1 barrier/tile) ----------------
__global__ __launch_bounds__(256, 2) void attn_k(
    const bf16_t* __restrict__ Qn, const bf16_t* __restrict__ Kn,
    const bf16_t* __restrict__ Vt, const bf16_t* __restrict__ biasb,
    const float* __restrict__ lsg, bf16_t* __restrict__ AO) {
    __shared__ __align__(16) unsigned char smem[65536];
    const int tid = threadIdx.x;
    const int w = tid >> 6, lane = tid & 63;
    const int lane31 = lane & 31, hi = lane >> 5;
    const int qb = blockIdx.x, bh = blockIdx.y;
    const int b = bh >> 4, h = bh & 15;
    const float lsc2 = __expf(fminf(lsg[h], LOGIT_SCALE_MAX_)) * LOG2E_;
    const int qr0 = qb * 128;
    const int qloc = w * 32 + lane31;
    const bf16_t* qrow  = Qn + (((long)b * H_ + h) * L_ + qr0 + qloc) * D_;
    const bf16_t* kbase = Kn + (((long)b * H_ + h) * L_) * D_;
    const bf16_t* vtbase = Vt + ((long)(b * H_ + h) * D_) * L_;
    const bf16_t* brow  = biasb + (long)(qr0 + qloc) * L_;

    const int ksr = tid >> 4, ksc = (tid & 15) * 8;
    const int vsr = tid >> 3, vsc = (tid & 7) * 8;

    bf16x8 qreg[8];
    #pragma unroll
    for (int kk = 0; kk < 8; ++kk)
        qreg[kk] = *(const bf16x8*)(qrow + kk * 16 + 8 * hi);

    f32x16 oacc[4] = {};
    float l_ = 0.f;

    bf16x8 kreg[4], vreg[4];
    #pragma unroll
    for (int it = 0; it < 4; ++it) {
        kreg[it] = *(const bf16x8*)(kbase + (long)(it * 16 + ksr) * D_ + ksc);
        vreg[it] = *(const bf16x8*)(vtbase + (long)(it * 32 + vsr) * L_ + vsc);
    }
    #pragma unroll
    for (int it = 0; it < 4; ++it) {
        *(bf16x8*)(smem + KSB(0, it * 16 + ksr, ksc * 2)) = kreg[it];
        *(bf16x8*)(smem + VSB(0, it * 32 + vsr, vsc * 2)) = vreg[it];
    }
    int p = 0;

    for (int kt = 0; kt < L_; kt += 64) {
        __syncthreads();
        const int ktn = (kt + 64 < L_) ? kt + 64 : 0;
        #pragma unroll
        for (int it = 0; it < 4; ++it) {
            kreg[it] = *(const bf16x8*)(kbase + (long)(ktn + it * 16 + ksr) * D_ + ksc);
            vreg[it] = *(const bf16x8*)(vtbase + (long)(it * 32 + vsr) * L_ + ktn + vsc);
        }
        bf16x4 bb[2][4];
        #pragma unroll
        for (int f = 0; f < 2; ++f)
            #pragma unroll
            for (int rr = 0; rr < 4; ++rr)
                bb[f][rr] = *(const bf16x4*)(brow + kt + f * 32 + rr * 8 + 4 * hi);
        f32x16 sacc[2] = {};
        __builtin_amdgcn_s_setprio(1);
        #pragma unroll
        for (int kk = 0; kk < 8; ++kk) {
            bf16x8 ak0 = *(const bf16x8*)(smem + KSB(p, lane31,      kk * 32 + 16 * hi));
            bf16x8 ak1 = *(const bf16x8*)(smem + KSB(p, 32 + lane31, kk * 32 + 16 * hi));
            sacc[0] = __builtin_amdgcn_mfma_f32_32x32x16_bf16(ak0, qreg[kk], sacc[0], 0, 0, 0);
            sacc[1] = __builtin_amdgcn_mfma_f32_32x32x16_bf16(ak1, qreg[kk], sacc[1], 0, 0, 0);
        }
        __builtin_amdgcn_s_setprio(0);
        float ps = 0.f;
        unsigned int wv[2][4][2];
        #pragma unroll
        for (int f = 0; f < 2; ++f)
            #pragma unroll
            for (int rr = 0; rr < 4; ++rr)
                #pragma unroll
                for (int wi = 0; wi < 2; ++wi) {
                    float pa = __builtin_amdgcn_exp2f(sacc[f][rr * 4 + wi * 2]     * lsc2 + (float)bb[f][rr][wi * 2]);
                    float pc = __builtin_amdgcn_exp2f(sacc[f][rr * 4 + wi * 2 + 1] * lsc2 + (float)bb[f][rr][wi * 2 + 1]);
                    ps += pa + pc;
                    bf16x2 t = { (bf16_t)pa, (bf16_t)pc };
                    wv[f][rr][wi] = __builtin_bit_cast(unsigned int, t);
                }
        ps += __shfl_xor(ps, 32);
        l_ += ps;
        bf16x8 pb_[4];
        #pragma unroll
        for (int kk = 0; kk < 4; ++kk) {
            const int f = kk >> 1;
            const int a2 = (kk & 1) * 2;
            unsigned int A0 = wv[f][a2][0],     A1 = wv[f][a2][1];
            unsigned int B0 = wv[f][a2 + 1][0], B1 = wv[f][a2 + 1][1];
            unsigned int own0  = hi ? B0 : A0;
            unsigned int own1  = hi ? B1 : A1;
            unsigned int send0 = hi ? A0 : B0;
            unsigned int send1 = hi ? A1 : B1;
            unsigned int recv0 = __shfl_xor(send0, 32);
            unsigned int recv1 = __shfl_xor(send1, 32);
            uint4 uu;
            uu.x = hi ? recv0 : own0;
            uu.y = hi ? recv1 : own1;
            uu.z = hi ? own0  : recv0;
            uu.w = hi ? own1  : recv1;
            pb_[kk] = __builtin_bit_cast(bf16x8, uu);
        }
        __builtin_amdgcn_s_setprio(1);
        #pragma unroll
        for (int df = 0; df < 4; ++df)
            #pragma unroll
            for (int kk = 0; kk < 4; ++kk) {
                bf16x8 av = *(const bf16x8*)(smem + VSB(p, df * 32 + lane31, kk * 32 + 16 * hi));
                oacc[df] = __builtin_amdgcn_mfma_f32_32x32x16_bf16(av, pb_[kk], oacc[df], 0, 0, 0);
            }
        __builtin_amdgcn_s_setprio(0);
        if (kt + 64 < L_) {
            #pragma unroll
            for (int it = 0; it < 4; ++it) {
                *(bf16x8*)(smem + KSB(p ^ 1, it * 16 + ksr, ksc * 2)) = kreg[it];
                *(bf16x8*)(smem + VSB(p ^ 1, it * 32 + vsr, vsc * 2)) = vreg[it];
            }
        }
        p ^= 1;
    }
    __syncthreads();
    float inv = 1.0f / l_;
    #pragma unroll
    for (int df = 0; df < 4; ++df)
        #pragma unroll
        for (int rg = 0; rg < 16; ++rg) {
            int d = df * 32 + (rg & 3) + 8 * (rg >> 2) + 4 * hi;
            *(bf16_t*)(smem + qloc * 264 + d * 2) = (bf16_t)(oacc[df][rg] * inv);
        }
    __syncthreads();
    #pragma unroll
    for (int it = 0; it < 8; ++it) {
        int idx = it * 256 + tid;
        int row = idx >> 4, c = idx & 15;
        bf16x8 v = *(const bf16x8*)(smem + row * 264 + c * 16);
        *(bf16x8*)(AO + ((long)b * L_ + qr0 + row) * E_ + h * D_ + c * 8) = v;
    }
}

extern "C" void kernel_launch(void* const* d_in, const int* in_sizes, int n_in,
                              void* d_out, int out_size, void* d_ws, size_t ws_size,
                              hipStream_t stream) {
    const float* inputs_q  = (const float*)d_in[0];
    const float* inputs_kv = (const float*)d_in[1];
    const float* bias      = (const float*)d_in[2];
    const float* q_sin     = (const float*)d_in[3];
    const float* k_sin     = (const float*)d_in[4];
    const float* Wq        = (const float*)d_in[5];
    const float* Wk        = (const float*)d_in[6];
    const float* Wv        = (const float*)d_in[7];
    const float* Wo        = (const float*)d_in[8];
    const float* qns       = (const float*)d_in[9];
    const float* kns       = (const float*)d_in[10];
    const float* lsg       = (const float*)d_in[11];

    bf16_t* ws = (bf16_t*)d_ws;
    const long NW = NW_;
    const long NX = NX_;
    bf16_t* Wq_b   = ws;                    // Wq,Wk,Wv contiguous
    bf16_t* Wo_b   = ws + 3 * NW;
    bf16_t* bias_b = ws + 4 * NW;
    bf16_t* Xq     = bias_b + NW;
    bf16_t* Xkv    = Xq + NX;
    bf16_t* Qp     = Xkv + NX;              // Qp,Kp,Vp contiguous for grouped GEMM
    bf16_t* Kp     = Qp + NX;
    bf16_t* Vp     = Kp + NX;
    bf16_t* Qn = Xq;    // alias (Xq dead after GEMM Q)
    bf16_t* Kn = Xkv;   // alias (Xkv dead after GEMMs)
    bf16_t* AO = Qp;    // alias (Qp dead after postproc Q)
    bf16_t* Vtr = Kp;   // alias (Kp dead after postproc K)
    if (ws_size < (size_t)(5 * NW + 5 * NX) * 2) return;

    {
        long n4 = (5 * NW + 2 * NX) / 4;
        cvt_all_k<<<dim3((unsigned)(n4 / 256)), dim3(256), 0, stream>>>(
            inputs_q, inputs_kv, bias, Wq, Wk, Wv, Wo, ws);
    }

    // grouped QKV projection, 8-phase 256x128 tiles (768 blocks = 3.0 rounds)
    gemm8<bf16_t, 3><<<dim3(768), dim3(512), 0, stream>>>(Xq, Xkv, Wq_b, Qp);

    post_tv_k<<<dim3(34816), dim3(256), 0, stream>>>(
        Qp, Kp, Vp, q_sin, k_sin, qns, kns, Qn, Kn, Vtr);

    attn_k<<<dim3(L_ / 128, B_ * H_), dim3(256), 0, stream>>>(Qn, Kn, Vtr, bias_b, lsg, AO);

    gemm8<float, 1><<<dim3(256), dim3(512), 0, stream>>>(AO, AO, Wo_b, (float*)d_out);
}

// Round 13
// 311.133 us; speedup vs baseline: 1.1058x; 1.0284x over previous
//
#include <hip/hip_runtime.h>
#include <hip/hip_bf16.h>

#define B_ 2
#define L_ 2048
#define E_ 2048
#define H_ 16
#define D_ 128
#define M_ (B_*L_)
#define LOGIT_SCALE_MAX_ 4.6051701859880914f
#define LOG2E_ 1.44269504088896f

typedef __bf16 bf16_t;
typedef __bf16 bf16x2 __attribute__((ext_vector_type(2)));
typedef __bf16 bf16x4 __attribute__((ext_vector_type(4)));
typedef __bf16 bf16x8 __attribute__((ext_vector_type(8)));
typedef float f32x4 __attribute__((ext_vector_type(4)));
typedef float f32x16 __attribute__((ext_vector_type(16)));

// attn LDS: double-buffered K (64x128 @256B rows) + V^T (128x64 @128B rows), 32KB per buffer
#define KSB(p, r, cb) ((p) * 32768 + (r) * 256 + ((cb) ^ (((r) & 7) << 4)))
#define VSB(p, r, cb) ((p) * 32768 + 16384 + (r) * 128 + ((cb) ^ (((r) & 7) << 4)))

#define NW_ 4194304L   // E*E
#define NX_ 8388608L   // M*E

// ---------------- fused fp32 -> bf16 convert of all 7 inputs ----------------
__global__ void cvt_all_k(const float* __restrict__ xq, const float* __restrict__ xkv,
                          const float* __restrict__ bias,
                          const float* __restrict__ wq, const float* __restrict__ wk,
                          const float* __restrict__ wv, const float* __restrict__ wo,
                          bf16_t* __restrict__ ws) {
    const long NW4 = NW_ / 4, NX4 = NX_ / 4;
    long i4 = (long)blockIdx.x * 256 + threadIdx.x;
    const float* src; long off; float scale = 1.0f;
    if (i4 < 4 * NW4) {
        long r = i4 / NW4;
        src = (r == 0) ? wq : (r == 1) ? wk : (r == 2) ? wv : wo;
        off = i4 - r * NW4;
    } else if (i4 < 5 * NW4) {
        src = bias; off = i4 - 4 * NW4; scale = LOG2E_;
    } else if (i4 < 5 * NW4 + NX4) {
        src = xq; off = i4 - 5 * NW4;
    } else {
        src = xkv; off = i4 - 5 * NW4 - NX4;
    }
    float4 v = ((const float4*)src)[off];
    bf16x4 o = { (bf16_t)(v.x * scale), (bf16_t)(v.y * scale),
                 (bf16_t)(v.z * scale), (bf16_t)(v.w * scale) };
    ((bf16x4*)ws)[i4] = o;
}

// ---------------- 256x256 8-wave 4-phase NT GEMM (m201-style counted-vmcnt pipeline) ----------------
// 8 waves (2M x 4N), wave tile 128x64. BK=64 as two kk subtiles [128][64B], swizzle c16^((row>>1)&3).
// LDS per buf 64KB: A[2 half][2 kk][128][64B] | B[same]; 2 bufs = 128KB.
// Stage schedule per tile t (buf p): ph0 A0(t+1)->p^1, ph1 A1(t+1)->p^1, ph2 B0(t+2)->p,
// ph3 B1(t+2)->p + vmcnt(4)  [retires exactly through A1(t+1); B leads 2 tiles].
template<typename OutT, int GROUPS>
__global__ __launch_bounds__(512, 2) void gemm256(
    const bf16_t* __restrict__ A0g, const bf16_t* __restrict__ A1g,
    const bf16_t* __restrict__ W0, OutT* __restrict__ C0) {
    __shared__ __align__(16) unsigned char smem[131072];
    const int tid = threadIdx.x;
    const int wid = tid >> 6, lane = tid & 63;
    const int fr = lane & 15, fq = lane >> 4;
    const int wm = wid >> 2, wn = wid & 3;        // 2M x 4N
    int bid = blockIdx.x;
    { int cpx = (int)gridDim.x >> 3; bid = (bid & 7) * cpx + (bid >> 3); }
    const int g = (GROUPS > 1) ? (bid >> 7) : 0;
    const int wg = (GROUPS > 1) ? (bid & 127) : bid;
    const int bm = wg >> 3, bn = wg & 7;
    const long arow0 = (long)bm * 256;
    const long brow0 = (long)bn * 256;
    const bf16_t* Ab = ((GROUPS > 1 && g > 0) ? A1g : A0g) + arow0 * E_;
    const bf16_t* Wb = W0 + (long)g * (long)E_ * E_ + brow0 * E_;

    f32x4 acc[8][4] = {};

    const int srow = tid >> 2;          // 0..127
    const int sc16 = tid & 3;
    // one half-tile stage = 2 gloads/thread (kk 0,1)
    auto STG = [&](const bf16_t* base, unsigned matOff, int h, unsigned bufb, int kt) {
        #pragma unroll
        for (int kk = 0; kk < 2; ++kk) {
            int col = kk * 32 + ((sc16 ^ ((srow >> 1) & 3)) * 8);
            __builtin_amdgcn_global_load_lds(
                (const __attribute__((address_space(1))) void*)(base + (long)(h * 128 + srow) * E_ + kt + col),
                (__attribute__((address_space(3))) void*)(smem + bufb + matOff + h * 16384u + kk * 8192u + tid * 16), 16, 0, 0);
        }
    };
    auto LDA = [&](unsigned pb, int kk, int mi) -> bf16x8 {
        int r = wm * 128 + mi * 16 + fr;
        int lr = r & 127;
        return *(const bf16x8*)(smem + pb + (unsigned)(r >> 7) * 16384u + kk * 8192u + lr * 64 + ((fq ^ ((lr >> 1) & 3)) << 4));
    };
    auto LDB = [&](unsigned pb, int kk, int ni) -> bf16x8 {
        int r = wn * 64 + ni * 16 + fr;
        int lr = r & 127;
        return *(const bf16x8*)(smem + pb + 32768u + (unsigned)(r >> 7) * 16384u + kk * 8192u + lr * 64 + ((fq ^ ((lr >> 1) & 3)) << 4));
    };

    // prologue: tile0 fully (A0,A1,B0,B1) + tile1 B0,B1 ; vmcnt(4) retires tile0
    STG(Ab, 0u,     0, 0u, 0); STG(Ab, 0u,     1, 0u, 0);
    STG(Wb, 32768u, 0, 0u, 0); STG(Wb, 32768u, 1, 0u, 0);
    STG(Wb, 32768u, 0, 65536u, 64); STG(Wb, 32768u, 1, 65536u, 64);
    asm volatile("s_waitcnt vmcnt(4)" ::: "memory");
    __builtin_amdgcn_s_barrier();

    bf16x8 bq[2][4];
    #pragma unroll 2
    for (int t = 0; t < 32; ++t) {
        const unsigned pb = (unsigned)(t & 1) * 65536u;
        const unsigned sbA = 65536u - pb;          // A(t+1) -> other buffer
        const int ktA = ((t + 1) & 31) * 64;
        const int ktB = ((t + 2) & 31) * 64;
        bf16x8 a[2][2];
        // ---- phase 0: B all + A mi0,1 ; stage A half0(t+1)
        #pragma unroll
        for (int kk = 0; kk < 2; ++kk) {
            a[kk][0] = LDA(pb, kk, 0); a[kk][1] = LDA(pb, kk, 1);
            #pragma unroll
            for (int ni = 0; ni < 4; ++ni) bq[kk][ni] = LDB(pb, kk, ni);
        }
        STG(Ab, 0u, 0, sbA, ktA);
        __builtin_amdgcn_s_barrier();
        asm volatile("s_waitcnt lgkmcnt(0)" ::: "memory");
        __builtin_amdgcn_sched_barrier(0);
        __builtin_amdgcn_s_setprio(1);
        #pragma unroll
        for (int kk = 0; kk < 2; ++kk)
            #pragma unroll
            for (int ni = 0; ni < 4; ++ni) {
                acc[0][ni] = __builtin_amdgcn_mfma_f32_16x16x32_bf16(a[kk][0], bq[kk][ni], acc[0][ni], 0, 0, 0);
                acc[1][ni] = __builtin_amdgcn_mfma_f32_16x16x32_bf16(a[kk][1], bq[kk][ni], acc[1][ni], 0, 0, 0);
            }
        __builtin_amdgcn_s_setprio(0);
        __builtin_amdgcn_s_barrier();
        // ---- phase 1: A mi2,3 ; stage A half1(t+1)
        #pragma unroll
        for (int kk = 0; kk < 2; ++kk) { a[kk][0] = LDA(pb, kk, 2); a[kk][1] = LDA(pb, kk, 3); }
        STG(Ab, 0u, 1, sbA, ktA);
        __builtin_amdgcn_s_barrier();
        asm volatile("s_waitcnt lgkmcnt(0)" ::: "memory");
        __builtin_amdgcn_sched_barrier(0);
        __builtin_amdgcn_s_setprio(1);
        #pragma unroll
        for (int kk = 0; kk < 2; ++kk)
            #pragma unroll
            for (int ni = 0; ni < 4; ++ni) {
                acc[2][ni] = __builtin_amdgcn_mfma_f32_16x16x32_bf16(a[kk][0], bq[kk][ni], acc[2][ni], 0, 0, 0);
                acc[3][ni] = __builtin_amdgcn_mfma_f32_16x16x32_bf16(a[kk][1], bq[kk][ni], acc[3][ni], 0, 0, 0);
            }
        __builtin_amdgcn_s_setprio(0);
        __builtin_amdgcn_s_barrier();
        // ---- phase 2: A mi4,5 ; stage B half0(t+2) into current buf (B reads done at ph0)
        #pragma unroll
        for (int kk = 0; kk < 2; ++kk) { a[kk][0] = LDA(pb, kk, 4); a[kk][1] = LDA(pb, kk, 5); }
        STG(Wb, 32768u, 0, pb, ktB);
        __builtin_amdgcn_s_barrier();
        asm volatile("s_waitcnt lgkmcnt(0)" ::: "memory");
        __builtin_amdgcn_sched_barrier(0);
        __builtin_amdgcn_s_setprio(1);
        #pragma unroll
        for (int kk = 0; kk < 2; ++kk)
            #pragma unroll
            for (int ni = 0; ni < 4; ++ni) {
                acc[4][ni] = __builtin_amdgcn_mfma_f32_16x16x32_bf16(a[kk][0], bq[kk][ni], acc[4][ni], 0, 0, 0);
                acc[5][ni] = __builtin_amdgcn_mfma_f32_16x16x32_bf16(a[kk][1], bq[kk][ni], acc[5][ni], 0, 0, 0);
            }
        __builtin_amdgcn_s_setprio(0);
        __builtin_amdgcn_s_barrier();
        // ---- phase 3: A mi6,7 ; stage B half1(t+2) ; vmcnt(4)
        #pragma unroll
        for (int kk = 0; kk < 2; ++kk) { a[kk][0] = LDA(pb, kk, 6); a[kk][1] = LDA(pb, kk, 7); }
        STG(Wb, 32768u, 1, pb, ktB);
        asm volatile("s_waitcnt vmcnt(4)" ::: "memory");
        __builtin_amdgcn_s_barrier();
        asm volatile("s_waitcnt lgkmcnt(0)" ::: "memory");
        __builtin_amdgcn_sched_barrier(0);
        __builtin_amdgcn_s_setprio(1);
        #pragma unroll
        for (int kk = 0; kk < 2; ++kk)
            #pragma unroll
            for (int ni = 0; ni < 4; ++ni) {
                acc[6][ni] = __builtin_amdgcn_mfma_f32_16x16x32_bf16(a[kk][0], bq[kk][ni], acc[6][ni], 0, 0, 0);
                acc[7][ni] = __builtin_amdgcn_mfma_f32_16x16x32_bf16(a[kk][1], bq[kk][ni], acc[7][ni], 0, 0, 0);
            }
        __builtin_amdgcn_s_setprio(0);
        __builtin_amdgcn_s_barrier();
    }
    asm volatile("s_waitcnt vmcnt(0)" ::: "memory");
    // C store
    OutT* Cg = C0 + (long)g * M_ * E_;
    #pragma unroll
    for (int mi = 0; mi < 8; ++mi) {
        #pragma unroll
        for (int i = 0; i < 4; ++i) {
            long row = arow0 + wm * 128 + mi * 16 + fq * 4 + i;
            OutT* crow = Cg + row * E_ + brow0 + wn * 64 + fr;
            #pragma unroll
            for (int ni = 0; ni < 4; ++ni)
                crow[ni * 16] = (OutT)acc[mi][ni][i];
        }
    }
}

// ---------------- O-projection GEMM (proven round-12 gemm8, 256x128, 4-phase) ----------------
template<typename OutT>
__global__ __launch_bounds__(512, 2) void gemm8o(
    const bf16_t* __restrict__ A0g, const bf16_t* __restrict__ W0, OutT* __restrict__ C0) {
    __shared__ __align__(16) unsigned char smem[98304];
    const int tid = threadIdx.x;
    const int wid = tid >> 6, lane = tid & 63;
    const int fr = lane & 15, fq = lane >> 4;
    const int wm = wid & 3, wn = wid >> 2;
    int bid = blockIdx.x;
    { int cpx = (int)gridDim.x >> 3; bid = (bid & 7) * cpx + (bid >> 3); }
    const int bm = bid >> 4, bn = bid & 15;
    const long arow0 = (long)bm * 256;
    const long brow0 = (long)bn * 128;
    const bf16_t* Ab = A0g + arow0 * E_;
    const bf16_t* Wb = W0 + brow0 * E_;

    f32x4 acc[4][4] = {};

    auto STAGE_A = [&](unsigned sbase, int kk, int j, int ktn_) {
        int row = j * 128 + (tid >> 2);
        int c16 = tid & 3;
        int col = kk * 32 + ((c16 ^ ((row >> 1) & 3)) * 8);
        __builtin_amdgcn_global_load_lds(
            (const __attribute__((address_space(1))) void*)(Ab + (long)row * E_ + ktn_ + col),
            (__attribute__((address_space(3))) void*)(smem + sbase + kk * 16384 + j * 8192 + tid * 16), 16, 0, 0);
    };
    auto STAGE_B = [&](unsigned sbase, int kk, int ktn_) {
        int row = tid >> 2;
        int c16 = tid & 3;
        int col = kk * 32 + ((c16 ^ ((row >> 1) & 3)) * 8);
        __builtin_amdgcn_global_load_lds(
            (const __attribute__((address_space(1))) void*)(Wb + (long)row * E_ + ktn_ + col),
            (__attribute__((address_space(3))) void*)(smem + sbase + 32768 + kk * 8192 + tid * 16), 16, 0, 0);
    };
    auto LDA = [&](unsigned pbase, int kk, int mi) -> bf16x8 {
        int row = wm * 64 + mi * 16 + fr;
        return *(const bf16x8*)(smem + pbase + kk * 16384 + row * 64 + ((fq ^ ((row >> 1) & 3)) << 4));
    };
    auto LDB = [&](unsigned pbase, int kk, int ni) -> bf16x8 {
        int row = wn * 64 + ni * 16 + fr;
        return *(const bf16x8*)(smem + pbase + 32768 + kk * 8192 + row * 64 + ((fq ^ ((row >> 1) & 3)) << 4));
    };

    STAGE_A(0, 0, 0, 0); STAGE_A(0, 0, 1, 0); STAGE_B(0, 0, 0);
    STAGE_A(0, 1, 0, 0); STAGE_A(0, 1, 1, 0); STAGE_B(0, 1, 0);
    asm volatile("s_waitcnt vmcnt(0)" ::: "memory");
    __builtin_amdgcn_s_barrier();

    #pragma unroll 2
    for (int t = 0; t < 32; ++t) {
        const unsigned pb = (unsigned)(t & 1) * 49152u;
        const unsigned sb = 49152u - pb;
        const int ktn = (t < 31) ? (t + 1) * 64 : 0;
        bf16x8 bq[4], a0, a1;
        a0 = LDA(pb, 0, 0); a1 = LDA(pb, 0, 1);
        bq[0] = LDB(pb, 0, 0); bq[1] = LDB(pb, 0, 1); bq[2] = LDB(pb, 0, 2); bq[3] = LDB(pb, 0, 3);
        STAGE_A(sb, 0, 0, ktn); STAGE_A(sb, 0, 1, ktn);
        __builtin_amdgcn_s_barrier();
        asm volatile("s_waitcnt lgkmcnt(0)" ::: "memory");
        __builtin_amdgcn_sched_barrier(0);
        __builtin_amdgcn_s_setprio(1);
        #pragma unroll
        for (int ni = 0; ni < 4; ++ni) {
            acc[0][ni] = __builtin_amdgcn_mfma_f32_16x16x32_bf16(a0, bq[ni], acc[0][ni], 0, 0, 0);
            acc[1][ni] = __builtin_amdgcn_mfma_f32_16x16x32_bf16(a1, bq[ni], acc[1][ni], 0, 0, 0);
        }
        __builtin_amdgcn_s_setprio(0);
        __builtin_amdgcn_s_barrier();
        a0 = LDA(pb, 0, 2); a1 = LDA(pb, 0, 3);
        STAGE_B(sb, 0, ktn);
        asm volatile("s_waitcnt vmcnt(3)" ::: "memory");
        __builtin_amdgcn_s_barrier();
        asm volatile("s_waitcnt lgkmcnt(0)" ::: "memory");
        __builtin_amdgcn_sched_barrier(0);
        __builtin_amdgcn_s_setprio(1);
        #pragma unroll
        for (int ni = 0; ni < 4; ++ni) {
            acc[2][ni] = __builtin_amdgcn_mfma_f32_16x16x32_bf16(a0, bq[ni], acc[2][ni], 0, 0, 0);
            acc[3][ni] = __builtin_amdgcn_mfma_f32_16x16x32_bf16(a1, bq[ni], acc[3][ni], 0, 0, 0);
        }
        __builtin_amdgcn_s_setprio(0);
        __builtin_amdgcn_s_barrier();
        a0 = LDA(pb, 1, 0); a1 = LDA(pb, 1, 1);
        bq[0] = LDB(pb, 1, 0); bq[1] = LDB(pb, 1, 1); bq[2] = LDB(pb, 1, 2); bq[3] = LDB(pb, 1, 3);
        STAGE_A(sb, 1, 0, ktn); STAGE_A(sb, 1, 1, ktn);
        __builtin_amdgcn_s_barrier();
        asm volatile("s_waitcnt lgkmcnt(0)" ::: "memory");
        __builtin_amdgcn_sched_barrier(0);
        __builtin_amdgcn_s_setprio(1);
        #pragma unroll
        for (int ni = 0; ni < 4; ++ni) {
            acc[0][ni] = __builtin_amdgcn_mfma_f32_16x16x32_bf16(a0, bq[ni], acc[0][ni], 0, 0, 0);
            acc[1][ni] = __builtin_amdgcn_mfma_f32_16x16x32_bf16(a1, bq[ni], acc[1][ni], 0, 0, 0);
        }
        __builtin_amdgcn_s_setprio(0);
        __builtin_amdgcn_s_barrier();
        a0 = LDA(pb, 1, 2); a1 = LDA(pb, 1, 3);
        STAGE_B(sb, 1, ktn);
        asm volatile("s_waitcnt vmcnt(3)" ::: "memory");
        __builtin_amdgcn_s_barrier();
        asm volatile("s_waitcnt lgkmcnt(0)" ::: "memory");
        __builtin_amdgcn_sched_barrier(0);
        __builtin_amdgcn_s_setprio(1);
        #pragma unroll
        for (int ni = 0; ni < 4; ++ni) {
            acc[2][ni] = __builtin_amdgcn_mfma_f32_16x16x32_bf16(a0, bq[ni], acc[2][ni], 0, 0, 0);
            acc[3][ni] = __builtin_amdgcn_mfma_f32_16x16x32_bf16(a1, bq[ni], acc[3][ni], 0, 0, 0);
        }
        __builtin_amdgcn_s_setprio(0);
        __builtin_amdgcn_s_barrier();
    }
    #pragma unroll
    for (int mi = 0; mi < 4; ++mi) {
        #pragma unroll
        for (int i = 0; i < 4; ++i) {
            long row = arow0 + wm * 64 + mi * 16 + fq * 4 + i;
            OutT* crow = C0 + row * E_ + brow0 + wn * 64 + fr;
            #pragma unroll
            for (int ni = 0; ni < 4; ++ni)
                crow[ni * 16] = (OutT)acc[mi][ni][i];
        }
    }
}

// ---------------- merged: Q/K postprocess (blocks 0..32767) + V transpose (blocks 32768..34815) ----------------
__global__ __launch_bounds__(256) void post_tv_k(
    const bf16_t* __restrict__ Pq, const bf16_t* __restrict__ Pk,
    const bf16_t* __restrict__ Vp,
    const float* __restrict__ qsins, const float* __restrict__ ksins,
    const float* __restrict__ qnscale, const float* __restrict__ knscale,
    bf16_t* __restrict__ outq, bf16_t* __restrict__ outk, bf16_t* __restrict__ Vt) {
    __shared__ bf16_t t[64 * 64];
    if (blockIdx.x < 32768) {
        const int wid = threadIdx.x >> 6, lane = threadIdx.x & 63;
        const int half = blockIdx.x >> 14;
        const long g = (long)(blockIdx.x & 16383) * 4 + wid;
        const bf16_t* P = half ? Pk : Pq;
        const float* sins = half ? ksins : qsins;
        const float* nscale = half ? knscale : qnscale;
        bf16_t* out = half ? outk : outq;
        const int h = (int)(g % H_);
        const long bl = g / H_;
        const int b = (int)(bl / L_), l = (int)(bl % L_);
        bf16x2 xv = *(const bf16x2*)(P + g * D_ + lane * 2);
        float x0 = (float)xv[0], x1 = (float)xv[1];
        float ss = x0 * x0 + x1 * x1;
        #pragma unroll
        for (int m = 1; m < 64; m <<= 1) ss += __shfl_xor(ss, m);
        float r = rsqrtf(ss * (1.0f / 128.0f) + 1e-6f);
        float y0 = x0 * r * nscale[lane * 2];
        float y1 = x1 * r * nscale[lane * 2 + 1];
        float2 cs = *(const float2*)(sins + bl * D_ + lane * 2);
        float z0 = y0 * cs.x - y1 * cs.y;
        float z1 = y1 * cs.x + y0 * cs.y;
        float n2 = z0 * z0 + z1 * z1;
        #pragma unroll
        for (int m = 1; m < 64; m <<= 1) n2 += __shfl_xor(n2, m);
        float inv = 1.0f / fmaxf(sqrtf(n2), 1e-12f);
        bf16x2 o = { (bf16_t)(z0 * inv), (bf16_t)(z1 * inv) };
        *(bf16x2*)(out + (((long)b * H_ + h) * L_ + l) * D_ + lane * 2) = o;
    } else {
        const int idx = blockIdx.x - 32768;
        const int lb = idx & 31;
        const int db = (idx >> 5) & 1;
        const int bh = idx >> 6;
        const int b = bh >> 4, h = bh & 15;
        const bf16_t* src = Vp + ((long)(b * L_ + lb * 64) * H_ + h) * D_ + db * 64;
        #pragma unroll
        for (int it = 0; it < 2; ++it) {
            int i = it * 256 + threadIdx.x;
            int r = i >> 3, c8 = i & 7;
            bf16x8 v = *(const bf16x8*)(src + (long)r * H_ * D_ + c8 * 8);
            *(bf16x8*)&t[r * 64 + (c8 ^ (r >> 3)) * 8] = v;
        }
        __syncthreads();
        bf16_t* dst = Vt + ((long)(b * H_ + h) * D_ + db * 64) * L_ + lb * 64;
        #pragma unroll
        for (int it = 0; it < 2; ++it) {
            int i = it * 256 + threadIdx.x;
            int d = i >> 3, l8 = i & 7;
            bf16x8 o;
            #pragma unroll
            for (int j = 0; j < 8; ++j) {
                int l = l8 * 8 + j;
                o[j] = t[l * 64 + ((d >> 3) ^ l8) * 8 + (d & 7)];
            }
            *(bf16x8*)(dst + (long)d * L_ + l8 * 8) = o;
        }
    }
}

// ---------------- flash attention (32x32 swapped, no-max softmax, 1 barrier/tile) ----------------
__global__ __launch_bounds__(256, 2) void attn_k(
    const bf16_t* __restrict__ Qn, const bf16_t* __restrict__ Kn,
    const bf16_t* __restrict__ Vt, const bf16_t* __restrict__ biasb,
    const float* __restrict__ lsg, bf16_t* __restrict__ AO) {
    __shared__ __align__(16) unsigned char smem[65536];
    const int tid = threadIdx.x;
    const int w = tid >> 6, lane = tid & 63;
    const int lane31 = lane & 31, hi = lane >> 5;
    const int qb = blockIdx.x, bh = blockIdx.y;
    const int b = bh >> 4, h = bh & 15;
    const float lsc2 = __expf(fminf(lsg[h], LOGIT_SCALE_MAX_)) * LOG2E_;
    const int qr0 = qb * 128;
    const int qloc = w * 32 + lane31;
    const bf16_t* qrow  = Qn + (((long)b * H_ + h) * L_ + qr0 + qloc) * D_;
    const bf16_t* kbase = Kn + (((long)b * H_ + h) * L_) * D_;
    const bf16_t* vtbase = Vt + ((long)(b * H_ + h) * D_) * L_;
    const bf16_t* brow  = biasb + (long)(qr0 + qloc) * L_;

    const int ksr = tid >> 4, ksc = (tid & 15) * 8;
    const int vsr = tid >> 3, vsc = (tid & 7) * 8;

    bf16x8 qreg[8];
    #pragma unroll
    for (int kk = 0; kk < 8; ++kk)
        qreg[kk] = *(const bf16x8*)(qrow + kk * 16 + 8 * hi);

    f32x16 oacc[4] = {};
    float l_ = 0.f;

    bf16x8 kreg[4], vreg[4];
    #pragma unroll
    for (int it = 0; it < 4; ++it) {
        kreg[it] = *(const bf16x8*)(kbase + (long)(it * 16 + ksr) * D_ + ksc);
        vreg[it] = *(const bf16x8*)(vtbase + (long)(it * 32 + vsr) * L_ + vsc);
    }
    #pragma unroll
    for (int it = 0; it < 4; ++it) {
        *(bf16x8*)(smem + KSB(0, it * 16 + ksr, ksc * 2)) = kreg[it];
        *(bf16x8*)(smem + VSB(0, it * 32 + vsr, vsc * 2)) = vreg[it];
    }
    int p = 0;

    for (int kt = 0; kt < L_; kt += 64) {
        __syncthreads();
        const int ktn = (kt + 64 < L_) ? kt + 64 : 0;
        #pragma unroll
        for (int it = 0; it < 4; ++it) {
            kreg[it] = *(const bf16x8*)(kbase + (long)(ktn + it * 16 + ksr) * D_ + ksc);
            vreg[it] = *(const bf16x8*)(vtbase + (long)(it * 32 + vsr) * L_ + ktn + vsc);
        }
        bf16x4 bb[2][4];
        #pragma unroll
        for (int f = 0; f < 2; ++f)
            #pragma unroll
            for (int rr = 0; rr < 4; ++rr)
                bb[f][rr] = *(const bf16x4*)(brow + kt + f * 32 + rr * 8 + 4 * hi);
        f32x16 sacc[2] = {};
        __builtin_amdgcn_s_setprio(1);
        #pragma unroll
        for (int kk = 0; kk < 8; ++kk) {
            bf16x8 ak0 = *(const bf16x8*)(smem + KSB(p, lane31,      kk * 32 + 16 * hi));
            bf16x8 ak1 = *(const bf16x8*)(smem + KSB(p, 32 + lane31, kk * 32 + 16 * hi));
            sacc[0] = __builtin_amdgcn_mfma_f32_32x32x16_bf16(ak0, qreg[kk], sacc[0], 0, 0, 0);
            sacc[1] = __builtin_amdgcn_mfma_f32_32x32x16_bf16(ak1, qreg[kk], sacc[1], 0, 0, 0);
        }
        __builtin_amdgcn_s_setprio(0);
        float ps = 0.f;
        unsigned int wv[2][4][2];
        #pragma unroll
        for (int f = 0; f < 2; ++f)
            #pragma unroll
            for (int rr = 0; rr < 4; ++rr)
                #pragma unroll
                for (int wi = 0; wi < 2; ++wi) {
                    float pa = __builtin_amdgcn_exp2f(sacc[f][rr * 4 + wi * 2]     * lsc2 + (float)bb[f][rr][wi * 2]);
                    float pc = __builtin_amdgcn_exp2f(sacc[f][rr * 4 + wi * 2 + 1] * lsc2 + (float)bb[f][rr][wi * 2 + 1]);
                    ps += pa + pc;
                    bf16x2 t = { (bf16_t)pa, (bf16_t)pc };
                    wv[f][rr][wi] = __builtin_bit_cast(unsigned int, t);
                }
        ps += __shfl_xor(ps, 32);
        l_ += ps;
        bf16x8 pb_[4];
        #pragma unroll
        for (int kk = 0; kk < 4; ++kk) {
            const int f = kk >> 1;
            const int a2 = (kk & 1) * 2;
            unsigned int A0 = wv[f][a2][0],     A1 = wv[f][a2][1];
            unsigned int B0 = wv[f][a2 + 1][0], B1 = wv[f][a2 + 1][1];
            unsigned int own0  = hi ? B0 : A0;
            unsigned int own1  = hi ? B1 : A1;
            unsigned int send0 = hi ? A0 : B0;
            unsigned int send1 = hi ? A1 : B1;
            unsigned int recv0 = __shfl_xor(send0, 32);
            unsigned int recv1 = __shfl_xor(send1, 32);
            uint4 uu;
            uu.x = hi ? recv0 : own0;
            uu.y = hi ? recv1 : own1;
            uu.z = hi ? own0  : recv0;
            uu.w = hi ? own1  : recv1;
            pb_[kk] = __builtin_bit_cast(bf16x8, uu);
        }
        __builtin_amdgcn_s_setprio(1);
        #pragma unroll
        for (int df = 0; df < 4; ++df)
            #pragma unroll
            for (int kk = 0; kk < 4; ++kk) {
                bf16x8 av = *(const bf16x8*)(smem + VSB(p, df * 32 + lane31, kk * 32 + 16 * hi));
                oacc[df] = __builtin_amdgcn_mfma_f32_32x32x16_bf16(av, pb_[kk], oacc[df], 0, 0, 0);
            }
        __builtin_amdgcn_s_setprio(0);
        if (kt + 64 < L_) {
            #pragma unroll
            for (int it = 0; it < 4; ++it) {
                *(bf16x8*)(smem + KSB(p ^ 1, it * 16 + ksr, ksc * 2)) = kreg[it];
                *(bf16x8*)(smem + VSB(p ^ 1, it * 32 + vsr, vsc * 2)) = vreg[it];
            }
        }
        p ^= 1;
    }
    __syncthreads();
    float inv = 1.0f / l_;
    #pragma unroll
    for (int df = 0; df < 4; ++df)
        #pragma unroll
        for (int rg = 0; rg < 16; ++rg) {
            int d = df * 32 + (rg & 3) + 8 * (rg >> 2) + 4 * hi;
            *(bf16_t*)(smem + qloc * 264 + d * 2) = (bf16_t)(oacc[df][rg] * inv);
        }
    __syncthreads();
    #pragma unroll
    for (int it = 0; it < 8; ++it) {
        int idx = it * 256 + tid;
        int row = idx >> 4, c = idx & 15;
        bf16x8 v = *(const bf16x8*)(smem + row * 264 + c * 16);
        *(bf16x8*)(AO + ((long)b * L_ + qr0 + row) * E_ + h * D_ + c * 8) = v;
    }
}

extern "C" void kernel_launch(void* const* d_in, const int* in_sizes, int n_in,
                              void* d_out, int out_size, void* d_ws, size_t ws_size,
                              hipStream_t stream) {
    const float* inputs_q  = (const float*)d_in[0];
    const float* inputs_kv = (const float*)d_in[1];
    const float* bias      = (const float*)d_in[2];
    const float* q_sin     = (const float*)d_in[3];
    const float* k_sin     = (const float*)d_in[4];
    const float* Wq        = (const float*)d_in[5];
    const float* Wk        = (const float*)d_in[6];
    const float* Wv        = (const float*)d_in[7];
    const float* Wo        = (const float*)d_in[8];
    const float* qns       = (const float*)d_in[9];
    const float* kns       = (const float*)d_in[10];
    const float* lsg       = (const float*)d_in[11];

    bf16_t* ws = (bf16_t*)d_ws;
    const long NW = NW_;
    const long NX = NX_;
    bf16_t* Wq_b   = ws;                    // Wq,Wk,Wv contiguous
    bf16_t* Wo_b   = ws + 3 * NW;
    bf16_t* bias_b = ws + 4 * NW;
    bf16_t* Xq     = bias_b + NW;
    bf16_t* Xkv    = Xq + NX;
    bf16_t* Qp     = Xkv + NX;              // Qp,Kp,Vp contiguous for grouped GEMM
    bf16_t* Kp     = Qp + NX;
    bf16_t* Vp     = Kp + NX;
    bf16_t* Qn = Xq;    // alias (Xq dead after GEMM Q)
    bf16_t* Kn = Xkv;   // alias (Xkv dead after GEMMs)
    bf16_t* AO = Qp;    // alias (Qp dead after postproc Q)
    bf16_t* Vtr = Kp;   // alias (Kp dead after postproc K)
    if (ws_size < (size_t)(5 * NW + 5 * NX) * 2) return;

    {
        long n4 = (5 * NW + 2 * NX) / 4;
        cvt_all_k<<<dim3((unsigned)(n4 / 256)), dim3(256), 0, stream>>>(
            inputs_q, inputs_kv, bias, Wq, Wk, Wv, Wo, ws);
    }

    // grouped QKV projection, 256x256 8-wave pipeline (384 blocks)
    gemm256<bf16_t, 3><<<dim3(384), dim3(512), 0, stream>>>(Xq, Xkv, Wq_b, Qp);

    post_tv_k<<<dim3(34816), dim3(256), 0, stream>>>(
        Qp, Kp, Vp, q_sin, k_sin, qns, kns, Qn, Kn, Vtr);

    attn_k<<<dim3(L_ / 128, B_ * H_), dim3(256), 0, stream>>>(Qn, Kn, Vtr, bias_b, lsg, AO);

    gemm8o<float><<<dim3(256), dim3(512), 0, stream>>>(AO, Wo_b, (float*)d_out);
}